// Round 1
// baseline (569.649 us; speedup 1.0000x reference)
//
#include <hip/hip_runtime.h>
#include <math.h>

#define B_    1024
#define N_    512
#define M_    128
#define CDIM_ 1024
#define OUT_  390   // 3*M + 6

__device__ __forceinline__ float softplus_f(float x) {
    return fmaxf(x, 0.f) + log1pf(expf(-fabsf(x)));
}
__device__ __forceinline__ float sigmoid_f(float x) {
    return 1.f / (1.f + expf(-x));
}

// ---------------------------------------------------------------------------
// Kernel 1: o[b, j] = sum_c hid[b,c] * W_fc[j,c] + b_fc[j]
// 32x32 tile SGEMM, 256 threads, 2x2 per thread. Grid (1024/32, ceil(390/32)).
// ---------------------------------------------------------------------------
__global__ __launch_bounds__(256) void fc_kernel(
    const float* __restrict__ hid, const float* __restrict__ W_fc,
    const float* __restrict__ b_fc, float* __restrict__ o)
{
    __shared__ float As[32][33];   // +1 pad: breaks same-bank row stride
    __shared__ float Bs[32][33];
    const int tid = threadIdx.x;
    const int bm = blockIdx.x, bn = blockIdx.y;
    const int ty = tid >> 4, tx = tid & 15;

    // staging coords: each thread loads one float4 per tile
    const int lrow = tid >> 3;        // 0..31
    const int lcol = (tid & 7) * 4;   // 0,4,...,28

    float acc00 = 0.f, acc01 = 0.f, acc10 = 0.f, acc11 = 0.f;

    const int arow = bm * 32 + lrow;        // < 1024 always
    const int jrow = bn * 32 + lrow;        // may exceed 389

    for (int kc = 0; kc < CDIM_; kc += 32) {
        float4 av = *(const float4*)(hid + (size_t)arow * CDIM_ + kc + lcol);
        float4 bv = make_float4(0.f, 0.f, 0.f, 0.f);
        if (jrow < OUT_)
            bv = *(const float4*)(W_fc + (size_t)jrow * CDIM_ + kc + lcol);
        As[lrow][lcol + 0] = av.x; As[lrow][lcol + 1] = av.y;
        As[lrow][lcol + 2] = av.z; As[lrow][lcol + 3] = av.w;
        Bs[lrow][lcol + 0] = bv.x; Bs[lrow][lcol + 1] = bv.y;
        Bs[lrow][lcol + 2] = bv.z; Bs[lrow][lcol + 3] = bv.w;
        __syncthreads();
#pragma unroll
        for (int kk = 0; kk < 32; ++kk) {
            float a0 = As[ty * 2 + 0][kk];
            float a1 = As[ty * 2 + 1][kk];
            float b0 = Bs[tx * 2 + 0][kk];
            float b1 = Bs[tx * 2 + 1][kk];
            acc00 += a0 * b0; acc01 += a0 * b1;
            acc10 += a1 * b0; acc11 += a1 * b1;
        }
        __syncthreads();
    }

    const int ob = bm * 32 + ty * 2;
    const int oj = bn * 32 + tx * 2;
    if (oj < OUT_) {
        float bias0 = b_fc[oj];
        o[(size_t)(ob + 0) * OUT_ + oj] = acc00 + bias0;
        o[(size_t)(ob + 1) * OUT_ + oj] = acc10 + bias0;
    }
    if (oj + 1 < OUT_) {
        float bias1 = b_fc[oj + 1];
        o[(size_t)(ob + 0) * OUT_ + oj + 1] = acc01 + bias1;
        o[(size_t)(ob + 1) * OUT_ + oj + 1] = acc11 + bias1;
    }
}

// ---------------------------------------------------------------------------
// Kernel 2: per-row activations. One block (128 threads) per b.
// splits: k=o[0:128], beta=o[128], g=o[129], s=o[130:133], gamma=o[133],
//         e=o[134:262], a=o[262:390]
// ---------------------------------------------------------------------------
__global__ __launch_bounds__(128) void act_kernel(
    const float* __restrict__ o,
    float* __restrict__ ws_k, float* __restrict__ ws_e,
    float* __restrict__ ws_a, float* __restrict__ params)
{
    const int b = blockIdx.x;
    const int tid = threadIdx.x;   // 0..127
    const float* orow = o + (size_t)b * OUT_;

    float kv = orow[tid] + 1e-16f;
    ws_k[(size_t)b * M_ + tid] = kv;

    float sq = kv * kv;
#pragma unroll
    for (int mask = 1; mask < 64; mask <<= 1) sq += __shfl_xor(sq, mask);
    __shared__ float red[2];
    if ((tid & 63) == 0) red[tid >> 6] = sq;

    float ev = sigmoid_f(orow[134 + tid]);
    ws_e[(size_t)b * M_ + tid] = ev;
    ws_a[(size_t)b * M_ + tid] = orow[262 + tid];

    __syncthreads();
    if (tid == 0) {
        float knorm = sqrtf(red[0] + red[1]);
        float beta  = softplus_f(orow[128]);
        float g     = sigmoid_f(orow[129]);
        float x0 = orow[130], x1 = orow[131], x2 = orow[132];
        float mx = fmaxf(x0, fmaxf(x1, x2));
        float e0 = expf(x0 - mx), e1 = expf(x1 - mx), e2 = expf(x2 - mx);
        float inv = 1.f / (e0 + e1 + e2);
        float gamma = 1.f + softplus_f(orow[133]);
        float* p = params + (size_t)b * 8;
        p[0] = beta; p[1] = g; p[2] = e0 * inv; p[3] = e1 * inv;
        p[4] = e2 * inv; p[5] = gamma; p[6] = knorm;
    }
}

// ---------------------------------------------------------------------------
// Kernel 3: content + location addressing. One block (256 thr, 4 waves) per b.
// Each wave handles 128 rows: coalesced float2/lane (512 B/row), shuffle-
// reduce dot & normsq together; then block softmax over N, interpolate,
// circular shift, sharpen (pow), renormalize -> w[b, :].
// ---------------------------------------------------------------------------
__global__ __launch_bounds__(256) void addr_kernel(
    const float* __restrict__ memory, const float* __restrict__ w_pre,
    const float* __restrict__ ws_k, const float* __restrict__ params,
    float* __restrict__ w_out)
{
    const int b = blockIdx.x;
    const int tid = threadIdx.x;
    const int lane = tid & 63;
    const int wave = tid >> 6;

    __shared__ float k_s[M_];
    __shared__ float Ks[N_];
    __shared__ float wgs[N_];
    __shared__ float red[8];

    if (tid < M_) k_s[tid] = ws_k[(size_t)b * M_ + tid];

    const float* p = params + (size_t)b * 8;
    const float beta = p[0], g = p[1], s0 = p[2], s1 = p[3], s2 = p[4];
    const float gamma = p[5], knorm = p[6];

    __syncthreads();

    const float kd0 = k_s[lane * 2 + 0];
    const float kd1 = k_s[lane * 2 + 1];

    // --- phase 1: dot + norm per row, wave-per-row ---
    const float* base = memory + (size_t)b * N_ * M_ + (size_t)(wave * 128) * M_ + lane * 2;
    float2 cur = *(const float2*)(base);
    for (int i = 0; i < 128; ++i) {
        const int ip = (i < 127) ? (i + 1) : 127;
        float2 nxt = *(const float2*)(base + (size_t)ip * M_);
        float m0 = cur.x + 1e-16f;
        float m1 = cur.y + 1e-16f;
        float dot = m0 * kd0 + m1 * kd1;
        float nrm = m0 * m0 + m1 * m1;
#pragma unroll
        for (int mask = 1; mask < 64; mask <<= 1) {
            dot += __shfl_xor(dot, mask);
            nrm += __shfl_xor(nrm, mask);
        }
        if (lane == 0) {
            float denom = fmaxf(sqrtf(nrm) * knorm, 1e-8f);
            Ks[wave * 128 + i] = beta * (dot / denom);
        }
        cur = nxt;
    }
    __syncthreads();

    // --- phase 2: softmax over N=512 (2 values per thread) ---
    float v0 = Ks[tid], v1 = Ks[tid + 256];
    float mx = fmaxf(v0, v1);
#pragma unroll
    for (int mask = 1; mask < 64; mask <<= 1) mx = fmaxf(mx, __shfl_xor(mx, mask));
    if (lane == 0) red[wave] = mx;
    __syncthreads();
    mx = fmaxf(fmaxf(red[0], red[1]), fmaxf(red[2], red[3]));

    float p0 = expf(v0 - mx), p1 = expf(v1 - mx);
    float sm = p0 + p1;
#pragma unroll
    for (int mask = 1; mask < 64; mask <<= 1) sm += __shfl_xor(sm, mask);
    if (lane == 0) red[4 + wave] = sm;
    __syncthreads();
    const float inv = 1.f / (red[4] + red[5] + red[6] + red[7]);

    // interpolate with previous weights
    float wp0 = w_pre[(size_t)b * N_ + tid];
    float wp1 = w_pre[(size_t)b * N_ + tid + 256];
    float wg0 = g * (p0 * inv) + (1.f - g) * wp0;
    float wg1 = g * (p1 * inv) + (1.f - g) * wp1;
    wgs[tid] = wg0;
    wgs[tid + 256] = wg1;
    __syncthreads();

    // --- phase 3: circular shift + sharpen ---
    // w_shift[n] = s0*wg[n-1] + s1*wg[n] + s2*wg[n+1]  (mod N)
    float t0 = s0 * wgs[(tid + 511) & 511] + s1 * wgs[tid] + s2 * wgs[(tid + 1) & 511];
    int n2 = tid + 256;
    float t1 = s0 * wgs[(n2 + 511) & 511] + s1 * wgs[n2] + s2 * wgs[(n2 + 1) & 511];

    float sh0 = powf(t0, gamma);
    float sh1 = powf(t1, gamma);

    float ssum = sh0 + sh1;
#pragma unroll
    for (int mask = 1; mask < 64; mask <<= 1) ssum += __shfl_xor(ssum, mask);
    if (lane == 0) red[wave] = ssum;
    __syncthreads();
    const float winv = 1.f / (red[0] + red[1] + red[2] + red[3] + 1e-16f);

    w_out[(size_t)b * N_ + tid] = sh0 * winv;
    w_out[(size_t)b * N_ + tid + 256] = sh1 * winv;
}

// ---------------------------------------------------------------------------
// Kernel 4: erase/add outer-product write, float4 elementwise.
// mem_new = memory*(1 - w[b,n]*e[b,m]) + w[b,n]*a[b,m]
// ---------------------------------------------------------------------------
__global__ __launch_bounds__(256) void write_kernel(
    const float* __restrict__ memory, const float* __restrict__ w,
    const float* __restrict__ ws_e, const float* __restrict__ ws_a,
    float* __restrict__ mem_out)
{
    const size_t idx = (size_t)blockIdx.x * 256 + threadIdx.x;  // float4 index
    // total = B*N*M/4 = 16777216; grid sized exactly
    const float4 mv = ((const float4*)memory)[idx];
    const int b   = (int)(idx >> 14);        // / (N*M/4 = 16384)
    const int rem = (int)(idx & 16383);
    const int n   = rem >> 5;                // / (M/4 = 32)
    const int m4  = rem & 31;

    const float wv = w[(size_t)b * N_ + n];
    const float4 ev = ((const float4*)ws_e)[(size_t)b * 32 + m4];
    const float4 av = ((const float4*)ws_a)[(size_t)b * 32 + m4];

    float4 ov;
    ov.x = mv.x * (1.f - wv * ev.x) + wv * av.x;
    ov.y = mv.y * (1.f - wv * ev.y) + wv * av.y;
    ov.z = mv.z * (1.f - wv * ev.z) + wv * av.z;
    ov.w = mv.w * (1.f - wv * ev.w) + wv * av.w;
    ((float4*)mem_out)[idx] = ov;
}

// ---------------------------------------------------------------------------
extern "C" void kernel_launch(void* const* d_in, const int* in_sizes, int n_in,
                              void* d_out, int out_size, void* d_ws, size_t ws_size,
                              hipStream_t stream)
{
    const float* hid    = (const float*)d_in[0];
    const float* w_pre  = (const float*)d_in[1];
    const float* memory = (const float*)d_in[2];
    const float* W_fc   = (const float*)d_in[3];
    const float* b_fc   = (const float*)d_in[4];

    float* out     = (float*)d_out;
    float* w_out   = out;                          // [B, N]
    float* mem_out = out + (size_t)B_ * N_;        // [B, N, M]

    float* ws     = (float*)d_ws;
    float* o      = ws;                      // B*OUT_ = 399360
    float* ws_k   = o    + (size_t)B_ * OUT_;
    float* ws_e   = ws_k + (size_t)B_ * M_;
    float* ws_a   = ws_e + (size_t)B_ * M_;
    float* params = ws_a + (size_t)B_ * M_;  // B*8

    dim3 g1(B_ / 32, (OUT_ + 31) / 32);      // 32 x 13
    fc_kernel<<<g1, 256, 0, stream>>>(hid, W_fc, b_fc, o);
    act_kernel<<<B_, 128, 0, stream>>>(o, ws_k, ws_e, ws_a, params);
    addr_kernel<<<B_, 256, 0, stream>>>(memory, w_pre, ws_k, params, w_out);

    const int total4 = B_ * N_ * M_ / 4;     // 16777216
    write_kernel<<<total4 / 256, 256, 0, stream>>>(memory, w_out, ws_e, ws_a, mem_out);
}

// Round 2
// 521.275 us; speedup vs baseline: 1.0928x; 1.0928x over previous
//
#include <hip/hip_runtime.h>
#include <math.h>

#define B_    1024
#define N_    512
#define M_    128
#define CDIM_ 1024
#define OUT_  390   // 3*M + 6
#define OUTP_ 448   // padded OUT (7 * 64)
#define SPLITK 4
#define KCH   (CDIM_ / SPLITK)   // 256

__device__ __forceinline__ float softplus_f(float x) {
    return fmaxf(x, 0.f) + log1pf(expf(-fabsf(x)));
}
__device__ __forceinline__ float sigmoid_f(float x) {
    return 1.f / (1.f + expf(-x));
}

// ---------------------------------------------------------------------------
// Kernel 1: split-K SGEMM partials: part[s][b][j] = sum_{k in chunk s} hid*W
// 64x64 tile, 256 threads, 4x4 per thread, 16-deep k subtiles.
// Grid (16, 7, 4) = 448 blocks.
// ---------------------------------------------------------------------------
__global__ __launch_bounds__(256) void fc_kernel(
    const float* __restrict__ hid, const float* __restrict__ W_fc,
    float* __restrict__ part)
{
    // stride 68 floats: 272 B keeps float4 alignment (272 % 16 == 0) and
    // gives 2-way (free) bank aliasing on the transposed stores.
    __shared__ float As[16][68];
    __shared__ float Bs[16][68];

    const int tid = threadIdx.x;
    const int bm = blockIdx.x, bn = blockIdx.y, bk = blockIdx.z;
    const int rb = bm * 64;          // hid row base
    const int jb = bn * 64;          // out-col base (W_fc row base)
    const int kb = bk * KCH;         // k base

    const int tx = tid & 15;         // 0..15 -> 4 cols each
    const int ty = tid >> 4;         // 0..15 -> 4 rows each

    const int srow = tid >> 2;       // 0..63  staging row
    const int scol = (tid & 3) * 4;  // 0,4,8,12 staging k-offset

    const int arow = rb + srow;
    const int jrow = jb + srow;
    const bool jvalid = (jrow < OUT_);

    float acc[4][4];
#pragma unroll
    for (int r = 0; r < 4; ++r)
#pragma unroll
        for (int c = 0; c < 4; ++c) acc[r][c] = 0.f;

    for (int kt = 0; kt < KCH; kt += 16) {
        float4 av = *(const float4*)(hid + (size_t)arow * CDIM_ + kb + kt + scol);
        float4 bv = make_float4(0.f, 0.f, 0.f, 0.f);
        if (jvalid)
            bv = *(const float4*)(W_fc + (size_t)jrow * CDIM_ + kb + kt + scol);
        As[scol + 0][srow] = av.x; As[scol + 1][srow] = av.y;
        As[scol + 2][srow] = av.z; As[scol + 3][srow] = av.w;
        Bs[scol + 0][srow] = bv.x; Bs[scol + 1][srow] = bv.y;
        Bs[scol + 2][srow] = bv.z; Bs[scol + 3][srow] = bv.w;
        __syncthreads();
#pragma unroll
        for (int k = 0; k < 16; ++k) {
            float4 a = *(const float4*)&As[k][ty * 4];
            float4 b = *(const float4*)&Bs[k][tx * 4];
            float ar[4] = {a.x, a.y, a.z, a.w};
            float br[4] = {b.x, b.y, b.z, b.w};
#pragma unroll
            for (int r = 0; r < 4; ++r)
#pragma unroll
                for (int c = 0; c < 4; ++c)
                    acc[r][c] += ar[r] * br[c];
        }
        __syncthreads();
    }

    float* pbase = part + (size_t)bk * B_ * OUTP_;
#pragma unroll
    for (int r = 0; r < 4; ++r) {
        float4 v = make_float4(acc[r][0], acc[r][1], acc[r][2], acc[r][3]);
        *(float4*)(pbase + (size_t)(rb + ty * 4 + r) * OUTP_ + jb + tx * 4) = v;
    }
}

// ---------------------------------------------------------------------------
// Kernel 2: sum split-K partials + bias + activations. One block (128 thr)/b.
// splits: k=[0:128], beta=128, g=129, s=130:133, gamma=133, e=134:262,
//         a=262:390
// ---------------------------------------------------------------------------
__global__ __launch_bounds__(128) void act_kernel(
    const float* __restrict__ part, const float* __restrict__ b_fc,
    float* __restrict__ ws_k, float* __restrict__ ws_e,
    float* __restrict__ ws_a, float* __restrict__ params)
{
    const int b = blockIdx.x;
    const int tid = threadIdx.x;   // 0..127
    const float* pb = part + (size_t)b * OUTP_;
    const size_t S = (size_t)B_ * OUTP_;

    float vk = b_fc[tid];
    float ve = b_fc[134 + tid];
    float va = b_fc[262 + tid];
#pragma unroll
    for (int s = 0; s < SPLITK; ++s) {
        vk += pb[s * S + tid];
        ve += pb[s * S + 134 + tid];
        va += pb[s * S + 262 + tid];
    }
    vk += 1e-16f;
    ws_k[(size_t)b * M_ + tid] = vk;
    ws_e[(size_t)b * M_ + tid] = sigmoid_f(ve);
    ws_a[(size_t)b * M_ + tid] = va;

    float sq = vk * vk;
#pragma unroll
    for (int mask = 1; mask < 64; mask <<= 1) sq += __shfl_xor(sq, mask);
    __shared__ float red[2];
    __shared__ float sscal[6];
    if ((tid & 63) == 0) red[tid >> 6] = sq;
    if (tid < 6) {
        float v = b_fc[128 + tid];
#pragma unroll
        for (int s = 0; s < SPLITK; ++s) v += pb[s * S + 128 + tid];
        sscal[tid] = v;
    }
    __syncthreads();
    if (tid == 0) {
        float knorm = sqrtf(red[0] + red[1]);
        float beta  = softplus_f(sscal[0]);
        float g     = sigmoid_f(sscal[1]);
        float x0 = sscal[2], x1 = sscal[3], x2 = sscal[4];
        float mx = fmaxf(x0, fmaxf(x1, x2));
        float e0 = expf(x0 - mx), e1 = expf(x1 - mx), e2 = expf(x2 - mx);
        float inv = 1.f / (e0 + e1 + e2);
        float gamma = 1.f + softplus_f(sscal[5]);
        float* p = params + (size_t)b * 8;
        p[0] = beta; p[1] = g; p[2] = e0 * inv; p[3] = e1 * inv;
        p[4] = e2 * inv; p[5] = gamma; p[6] = knorm;
    }
}

// ---------------------------------------------------------------------------
// Kernel 3 (fused): content+location addressing, then erase/add write.
// One block (256 thr, 4 waves) per b.
// Phase 1: 16 lanes/row, 8 contiguous floats/lane, 4-step shuffle reduce
//          (2 shuffles per row vs 12 in the wave-per-row version).
// Phase 2/3: softmax over N, interpolate, circular shift, sharpen, renorm.
// Phase 4: stream the same memory slice again (L2/L3-warm) for the write.
// ---------------------------------------------------------------------------
__global__ __launch_bounds__(256) void addr_write_kernel(
    const float* __restrict__ memory, const float* __restrict__ w_pre,
    const float* __restrict__ ws_k, const float* __restrict__ ws_e,
    const float* __restrict__ ws_a, const float* __restrict__ params,
    float* __restrict__ w_out, float* __restrict__ mem_out)
{
    const int b = blockIdx.x;
    const int tid = threadIdx.x;
    const int lane = tid & 63;
    const int wave = tid >> 6;

    __shared__ __align__(16) float k_s[M_];
    __shared__ __align__(16) float e_s[M_];
    __shared__ __align__(16) float a_s[M_];
    __shared__ float Ks[N_];
    __shared__ float wgs[N_];
    __shared__ float ws_f[N_];
    __shared__ float red[8];

    if (tid < M_) {
        k_s[tid] = ws_k[(size_t)b * M_ + tid];
        e_s[tid] = ws_e[(size_t)b * M_ + tid];
        a_s[tid] = ws_a[(size_t)b * M_ + tid];
    }

    const float* p = params + (size_t)b * 8;
    const float beta = p[0], g = p[1], s0 = p[2], s1 = p[3], s2 = p[4];
    const float gamma = p[5], knorm = p[6];

    __syncthreads();

    // --- phase 1: dot + normsq, 16 lanes per row, 4 rows per wave-iter ---
    const int sub = lane >> 4;        // 0..3: row within group of 4
    const int j16 = lane & 15;        // 0..15: 8-float chunk within row
    float kd[8];
#pragma unroll
    for (int t = 0; t < 8; ++t) kd[t] = k_s[j16 * 8 + t];

    const float* mb = memory + (size_t)b * N_ * M_;
#pragma unroll 2
    for (int i = 0; i < 32; ++i) {
        const int n = wave * 128 + i * 4 + sub;
        const float* rowp = mb + (size_t)n * M_ + j16 * 8;
        float4 x0 = *(const float4*)(rowp);
        float4 x1 = *(const float4*)(rowp + 4);
        float xv[8] = {x0.x, x0.y, x0.z, x0.w, x1.x, x1.y, x1.z, x1.w};
        float dot = 0.f, nrm = 0.f;
#pragma unroll
        for (int t = 0; t < 8; ++t) {
            float m = xv[t] + 1e-16f;
            dot += m * kd[t];
            nrm += m * m;
        }
#pragma unroll
        for (int mask = 1; mask < 16; mask <<= 1) {
            dot += __shfl_xor(dot, mask);
            nrm += __shfl_xor(nrm, mask);
        }
        if (j16 == 0) {
            float denom = fmaxf(sqrtf(nrm) * knorm, 1e-8f);
            Ks[n] = beta * (dot / denom);
        }
    }
    __syncthreads();

    // --- phase 2: softmax over N=512 (2 values per thread) ---
    float v0 = Ks[tid], v1 = Ks[tid + 256];
    float mx = fmaxf(v0, v1);
#pragma unroll
    for (int mask = 1; mask < 64; mask <<= 1) mx = fmaxf(mx, __shfl_xor(mx, mask));
    if (lane == 0) red[wave] = mx;
    __syncthreads();
    mx = fmaxf(fmaxf(red[0], red[1]), fmaxf(red[2], red[3]));

    float p0 = expf(v0 - mx), p1 = expf(v1 - mx);
    float sm = p0 + p1;
#pragma unroll
    for (int mask = 1; mask < 64; mask <<= 1) sm += __shfl_xor(sm, mask);
    if (lane == 0) red[4 + wave] = sm;
    __syncthreads();
    const float inv = 1.f / (red[4] + red[5] + red[6] + red[7]);

    float wp0 = w_pre[(size_t)b * N_ + tid];
    float wp1 = w_pre[(size_t)b * N_ + tid + 256];
    float wg0 = g * (p0 * inv) + (1.f - g) * wp0;
    float wg1 = g * (p1 * inv) + (1.f - g) * wp1;
    wgs[tid] = wg0;
    wgs[tid + 256] = wg1;
    __syncthreads();

    // --- phase 3: circular shift + sharpen + renormalize ---
    float t0 = s0 * wgs[(tid + 511) & 511] + s1 * wgs[tid] + s2 * wgs[(tid + 1) & 511];
    const int n2 = tid + 256;
    float t1 = s0 * wgs[(n2 + 511) & 511] + s1 * wgs[n2] + s2 * wgs[(n2 + 1) & 511];

    float sh0 = powf(t0, gamma);
    float sh1 = powf(t1, gamma);

    float ssum = sh0 + sh1;
#pragma unroll
    for (int mask = 1; mask < 64; mask <<= 1) ssum += __shfl_xor(ssum, mask);
    if (lane == 0) red[wave] = ssum;
    __syncthreads();
    const float winv = 1.f / (red[0] + red[1] + red[2] + red[3] + 1e-16f);

    float wf0 = sh0 * winv;
    float wf1 = sh1 * winv;
    w_out[(size_t)b * N_ + tid] = wf0;
    w_out[(size_t)b * N_ + tid + 256] = wf1;
    ws_f[tid] = wf0;
    ws_f[tid + 256] = wf1;
    __syncthreads();

    // --- phase 4: erase/add write, float4 streaming over this b's slice ---
    const float4* min4 = (const float4*)(mb);
    float4* mout4 = (float4*)(mem_out + (size_t)b * N_ * M_);
    const float4* e4 = (const float4*)e_s;
    const float4* a4 = (const float4*)a_s;
#pragma unroll 2
    for (int i = 0; i < 64; ++i) {
        const int idx = i * 256 + tid;       // 0..16383 float4 slots
        const int n   = idx >> 5;            // / 32
        const int m4  = idx & 31;
        float4 mv = min4[idx];
        float wv = ws_f[n];
        float4 ev = e4[m4];
        float4 av = a4[m4];
        float4 ov;
        ov.x = mv.x * (1.f - wv * ev.x) + wv * av.x;
        ov.y = mv.y * (1.f - wv * ev.y) + wv * av.y;
        ov.z = mv.z * (1.f - wv * ev.z) + wv * av.z;
        ov.w = mv.w * (1.f - wv * ev.w) + wv * av.w;
        mout4[idx] = ov;
    }
}

// ---------------------------------------------------------------------------
extern "C" void kernel_launch(void* const* d_in, const int* in_sizes, int n_in,
                              void* d_out, int out_size, void* d_ws, size_t ws_size,
                              hipStream_t stream)
{
    const float* hid    = (const float*)d_in[0];
    const float* w_pre  = (const float*)d_in[1];
    const float* memory = (const float*)d_in[2];
    const float* W_fc   = (const float*)d_in[3];
    const float* b_fc   = (const float*)d_in[4];

    float* out     = (float*)d_out;
    float* w_out   = out;                          // [B, N]
    float* mem_out = out + (size_t)B_ * N_;        // [B, N, M]

    float* ws     = (float*)d_ws;
    float* part   = ws;                                  // SPLITK*B*OUTP_
    float* ws_k   = part + (size_t)SPLITK * B_ * OUTP_;
    float* ws_e   = ws_k + (size_t)B_ * M_;
    float* ws_a   = ws_e + (size_t)B_ * M_;
    float* params = ws_a + (size_t)B_ * M_;              // B*8

    dim3 g1(B_ / 64, OUTP_ / 64, SPLITK);     // 16 x 7 x 4 = 448 blocks
    fc_kernel<<<g1, 256, 0, stream>>>(hid, W_fc, part);
    act_kernel<<<B_, 128, 0, stream>>>(part, b_fc, ws_k, ws_e, ws_a, params);
    addr_write_kernel<<<B_, 256, 0, stream>>>(memory, w_pre, ws_k, ws_e, ws_a,
                                              params, w_out, mem_out);
}